// Round 7
// baseline (441.504 us; speedup 1.0000x reference)
//
#include <hip/hip_runtime.h>
#include <hip/hip_bf16.h>

typedef __attribute__((ext_vector_type(8))) short bf16x8;
typedef __attribute__((ext_vector_type(4))) short s16x4;
typedef __attribute__((ext_vector_type(4))) float f32x4;

// LDS: 32 KB total, 4 blocks/CU (VGPR-capped at 16 waves).
// proj1: per-wave X strip, dbuf: wave w bytes [w*8192, w*8192+8192): 2 x [16 rows][64 f32],
//        row r at +r*256, 16B-slot s holds global slot s^r (XOR swizzle, source-side).
// post-proj1 alias (shorts): K[64][72] @0 ; VT[64][72] @4608 ; per-wave scratch[1280] @9216+wid*1280
//        (scratch: Q strip [16][72] -> PT [64][20] -> Y strip [16][72], sequential per-wave reuse)
#define LDS_BYTES 32768

__device__ __forceinline__ short f2b(float f) {
    __hip_bfloat16 h = __float2bfloat16(f);
    return __builtin_bit_cast(short, h);
}

__global__ void cvt_weights(const float* __restrict__ W1, const float* __restrict__ W2,
                            short* __restrict__ w1b, short* __restrict__ w2b) {
    int i = blockIdx.x * 256 + threadIdx.x;
    if (i < 192 * 768) w1b[i] = f2b(W1[i]);
    if (i < 768 * 64)  w2b[i] = f2b(W2[i]);
}

template<bool WSB>
__device__ __forceinline__ bf16x8 loadW(const short* __restrict__ wb,
                                        const float* __restrict__ wf, int off) {
    if (WSB) {
        return *(const bf16x8*)(wb + off);
    } else {
        f32x4 a = *(const f32x4*)(wf + off);
        f32x4 b = *(const f32x4*)(wf + off + 4);
        bf16x8 r;
        r[0] = f2b(a[0]); r[1] = f2b(a[1]); r[2] = f2b(a[2]); r[3] = f2b(a[3]);
        r[4] = f2b(b[0]); r[5] = f2b(b[1]); r[6] = f2b(b[2]); r[7] = f2b(b[3]);
        return r;
    }
}

__device__ __forceinline__ void gload_lds16(const float* g, unsigned char* l) {
    __builtin_amdgcn_global_load_lds(
        (const __attribute__((address_space(1))) void*)g,
        (__attribute__((address_space(3))) void*)l, 16, 0, 0);
}

#define VMWAIT(n) asm volatile("s_waitcnt vmcnt(" #n ")" ::: "memory")
#define LGKM0()   asm volatile("s_waitcnt lgkmcnt(0)" ::: "memory")

// One block per window, 4 waves. Wave w owns rows 16w..16w+15 for EVERYTHING:
// proj1 (all 192 o), its own Q, attn q-rows, out rows. proj1 is barrier-free.
template<bool WSB>
__global__ __launch_bounds__(256, 4)
void tiny_att(const float* __restrict__ x, const float* __restrict__ W1f,
              const float* __restrict__ b1v, const float* __restrict__ W2f,
              const float* __restrict__ b2v, const short* __restrict__ W1b,
              const short* __restrict__ W2b, float* __restrict__ out) {
    __shared__ __align__(16) unsigned char L[LDS_BYTES];
    short* S = (short*)L;
    const int tid  = threadIdx.x;
    const int wid  = tid >> 6;
    const int lane = tid & 63;
    const int g    = lane >> 4;
    const int c    = lane & 15;
    const int win  = blockIdx.x;
    const float* xg = x + (size_t)win * (64 * 768);
    const int xsb = wid * 8192;          // wave's X strip base (bytes)
    const int pw  = 9216 + wid * 1280;   // wave's scratch base (shorts)
    const f32x4 zero4 = {0.f, 0.f, 0.f, 0.f};

    // ---------------- proj1: rows 16w..16w+15, QKV[16][192], barrier-free ----------------
    f32x4 acc1[12];
    #pragma unroll
    for (int i = 0; i < 12; ++i) acc1[i] = zero4;

    // stage chunk kc (64 f32 cols of the wave's 16 rows) into buf b
    auto STAGE = [&](int kc, int b) {
        #pragma unroll
        for (int j = 0; j < 4; ++j) {
            int rr = j * 4 + g;                       // strip row 0..15
            const float* gsrc = xg + (16 * wid + rr) * 768 + kc * 64 + ((c ^ rr) << 2);
            gload_lds16(gsrc, &L[xsb + b * 4096 + j * 1024]);   // dest wave-uniform + lane*16
        }
    };
    // A-frag (row c, k = ks*32+8g .. +8) from buf b, un-swizzle on read
    auto LDA = [&](int b, int ks) -> bf16x8 {
        const unsigned char* Lb = &L[xsb + b * 4096 + c * 256];
        int s0 = ks * 8 + 2 * g;                      // even 16B slot
        f32x4 lo = *(const f32x4*)(Lb + ((s0 ^ c) << 4));
        f32x4 hi = *(const f32x4*)(Lb + (((s0 ^ 1) ^ c) << 4));
        bf16x8 a;
        a[0] = f2b(lo[0]); a[1] = f2b(lo[1]); a[2] = f2b(lo[2]); a[3] = f2b(lo[3]);
        a[4] = f2b(hi[0]); a[5] = f2b(hi[1]); a[6] = f2b(hi[2]); a[7] = f2b(hi[3]);
        return a;
    };

    STAGE(0, 0);
    STAGE(1, 1);
    #pragma unroll 1
    for (int kc = 0; kc < 12; ++kc) {
        const int b = kc & 1;
        if (kc < 11) { VMWAIT(4); } else { VMWAIT(0); }   // stage(kc) landed; stage(kc+1) may fly
        __builtin_amdgcn_sched_barrier(0);
        bf16x8 A0 = LDA(b, 0);
        bf16x8 A1 = LDA(b, 1);
        LGKM0();                                          // strip reads retired before overwrite
        __builtin_amdgcn_sched_barrier(0);
        if (kc + 2 < 12) STAGE(kc + 2, b);
        #pragma unroll
        for (int ks = 0; ks < 2; ++ks) {
            bf16x8 Af = ks ? A1 : A0;
            #pragma unroll
            for (int h = 0; h < 2; ++h) {                 // 6 o-tiles per half (24 W VGPRs live)
                bf16x8 w[6];
                #pragma unroll
                for (int t = 0; t < 6; ++t)
                    w[t] = loadW<WSB>(W1b, W1f, (16 * (h * 6 + t) + c) * 768 + kc * 64 + ks * 32 + 8 * g);
                #pragma unroll
                for (int t = 0; t < 6; ++t)
                    acc1[h * 6 + t] = __builtin_amdgcn_mfma_f32_16x16x32_bf16(
                        Af, w[t], acc1[h * 6 + t], 0, 0, 0);
            }
        }
    }
    __syncthreads();   // all waves done with X strips -> attn regions may alias them

    // ---------------- bias + Q(private) / K / VT -> LDS ----------------
    // acc1[oi][r] = QKV[n = 16wid+4g+r][o = 16oi+c]
    #pragma unroll
    for (int oi = 0; oi < 12; ++oi) {
        int o = 16 * oi + c;
        float bias = b1v[o];
        f32x4 v = acc1[oi];
        if (oi < 4) {              // Q -> private strip [q-local][d], stride 72
            #pragma unroll
            for (int r = 0; r < 4; ++r)
                S[pw + (4 * g + r) * 72 + o] = f2b(v[r] + bias);
        } else if (oi < 8) {       // K[n][d] shared, stride 72
            int d = o - 64;
            #pragma unroll
            for (int r = 0; r < 4; ++r)
                S[(16 * wid + 4 * g + r) * 72 + d] = f2b(v[r] + bias);
        } else {                   // VT[d][n] shared, stride 72 (packed along n)
            int d = o - 128;
            s16x4 sv;
            sv[0] = f2b(v[0] + bias); sv[1] = f2b(v[1] + bias);
            sv[2] = f2b(v[2] + bias); sv[3] = f2b(v[3] + bias);
            *(s16x4*)&S[4608 + d * 72 + 16 * wid + 4 * g] = sv;
        }
    }
    __syncthreads();   // K/VT visible; last barrier in the kernel

    // ---------------- S = Q K^T for q-rows 16wid..+15 ----------------
    f32x4 sc[4];
    #pragma unroll
    for (int mt = 0; mt < 4; ++mt) sc[mt] = zero4;
    #pragma unroll
    for (int ks = 0; ks < 2; ++ks) {
        bf16x8 aq = *(const bf16x8*)&S[pw + c * 72 + ks * 32 + 8 * g];
        #pragma unroll
        for (int mt = 0; mt < 4; ++mt) {
            bf16x8 bk = *(const bf16x8*)&S[(16 * mt + c) * 72 + ks * 32 + 8 * g];
            sc[mt] = __builtin_amdgcn_mfma_f32_16x16x32_bf16(aq, bk, sc[mt], 0, 0, 0);
        }
    }

    // ---------------- softmax over n (lane holds S[q=4g+r][n=16mt+c]) ----------------
    float p[4][4];
    const float kS = 0.125f * 1.44269504088896f;   // 1/sqrt(64) * log2(e)
    #pragma unroll
    for (int r = 0; r < 4; ++r) {
        float m0 = fmaxf(fmaxf(sc[0][r], sc[1][r]), fmaxf(sc[2][r], sc[3][r]));
        m0 = fmaxf(m0, __shfl_xor(m0, 1));
        m0 = fmaxf(m0, __shfl_xor(m0, 2));
        m0 = fmaxf(m0, __shfl_xor(m0, 4));
        m0 = fmaxf(m0, __shfl_xor(m0, 8));
        float s0 = 0.f;
        float pr[4];
        #pragma unroll
        for (int mt = 0; mt < 4; ++mt) { pr[mt] = exp2f((sc[mt][r] - m0) * kS); s0 += pr[mt]; }
        s0 += __shfl_xor(s0, 1);
        s0 += __shfl_xor(s0, 2);
        s0 += __shfl_xor(s0, 4);
        s0 += __shfl_xor(s0, 8);
        float inv = __builtin_amdgcn_rcpf(s0);
        #pragma unroll
        for (int mt = 0; mt < 4; ++mt) p[mt][r] = pr[mt] * inv;
    }

    // ---------------- P^T -> private scratch (aliases Q strip; Q reads done) ----------------
    #pragma unroll
    for (int mt = 0; mt < 4; ++mt) {
        s16x4 sv;
        sv[0] = f2b(p[mt][0]); sv[1] = f2b(p[mt][1]);
        sv[2] = f2b(p[mt][2]); sv[3] = f2b(p[mt][3]);
        *(s16x4*)&S[pw + (16 * mt + c) * 20 + 4 * g] = sv;
    }

    // ---------------- Y^T = V^T @ P^T ----------------
    f32x4 y4[4];
    #pragma unroll
    for (int it = 0; it < 4; ++it) y4[it] = zero4;
    #pragma unroll
    for (int ks = 0; ks < 2; ++ks) {
        bf16x8 pb;
        #pragma unroll
        for (int j = 0; j < 8; ++j)
            pb[j] = S[pw + (32 * ks + 8 * g + j) * 20 + c];
        #pragma unroll
        for (int it = 0; it < 4; ++it) {
            bf16x8 av = *(const bf16x8*)&S[4608 + (16 * it + c) * 72 + 32 * ks + 8 * g];
            y4[it] = __builtin_amdgcn_mfma_f32_16x16x32_bf16(av, pb, y4[it], 0, 0, 0);
        }
    }
    // Y repack via private strip (aliases PT; PT reads done)
    #pragma unroll
    for (int it = 0; it < 4; ++it) {
        s16x4 sv;
        sv[0] = f2b(y4[it][0]); sv[1] = f2b(y4[it][1]);
        sv[2] = f2b(y4[it][2]); sv[3] = f2b(y4[it][3]);
        *(s16x4*)&S[pw + c * 72 + 16 * it + 4 * g] = sv;
    }
    bf16x8 ay0 = *(const bf16x8*)&S[pw + c * 72 + 8 * g];
    bf16x8 ay1 = *(const bf16x8*)&S[pw + c * 72 + 32 + 8 * g];

    // ---------------- proj2: out rows 16wid..+15, barrier-free ----------------
    float* orow = out + ((size_t)win * 64 + 16 * wid) * 768;
    #pragma unroll 1
    for (int ch = 0; ch < 6; ++ch) {
        f32x4 a2[8];
        #pragma unroll
        for (int i = 0; i < 8; ++i) a2[i] = zero4;
        #pragma unroll
        for (int oi = 0; oi < 8; ++oi) {
            int off = (16 * (ch * 8 + oi) + c) * 64;
            bf16x8 bw0 = loadW<WSB>(W2b, W2f, off + 8 * g);
            a2[oi] = __builtin_amdgcn_mfma_f32_16x16x32_bf16(ay0, bw0, a2[oi], 0, 0, 0);
            bf16x8 bw1 = loadW<WSB>(W2b, W2f, off + 32 + 8 * g);
            a2[oi] = __builtin_amdgcn_mfma_f32_16x16x32_bf16(ay1, bw1, a2[oi], 0, 0, 0);
        }
        #pragma unroll
        for (int oi = 0; oi < 8; ++oi) {
            int o = 16 * (ch * 8 + oi) + c;
            float bias = b2v[o];
            #pragma unroll
            for (int r = 0; r < 4; ++r)
                orow[(size_t)(4 * g + r) * 768 + o] = a2[oi][r] + bias;
        }
    }
}

extern "C" void kernel_launch(void* const* d_in, const int* in_sizes, int n_in,
                              void* d_out, int out_size, void* d_ws, size_t ws_size,
                              hipStream_t stream) {
    const float* x  = (const float*)d_in[0];
    const float* W1 = (const float*)d_in[1];
    const float* b1 = (const float*)d_in[2];
    const float* W2 = (const float*)d_in[3];
    const float* b2 = (const float*)d_in[4];
    float* out = (float*)d_out;
    const int nwin = in_sizes[0] / (64 * 768);   // 2048 windows
    const size_t need = (size_t)(192 * 768 + 768 * 64) * sizeof(short);
    if (ws_size >= need) {
        short* w1b = (short*)d_ws;
        short* w2b = w1b + 192 * 768;
        cvt_weights<<<576, 256, 0, stream>>>(W1, W2, w1b, w2b);
        tiny_att<true><<<nwin, 256, 0, stream>>>(x, W1, b1, W2, b2, w1b, w2b, out);
    } else {
        tiny_att<false><<<nwin, 256, 0, stream>>>(x, W1, b1, W2, b2, nullptr, nullptr, out);
    }
}

// Round 8
// 282.428 us; speedup vs baseline: 1.5632x; 1.5632x over previous
//
#include <hip/hip_runtime.h>
#include <hip/hip_bf16.h>

typedef __attribute__((ext_vector_type(8))) short bf16x8;
typedef __attribute__((ext_vector_type(4))) short s16x4;
typedef __attribute__((ext_vector_type(4))) float f32x4;

// LDS layout (bytes):
//  [0, 32768)     X double-buffer: 2 x [64 rows][64 f32] LINEAR (global_load_lds dest),
//                 16B-slot index XOR-swizzled on the SOURCE side (both-sides rule)
//  [32768, 49152) QK bf16 [64][128] (Q cols 0..63, K cols 64..127)
//  post-proj1 alias into X region (shorts): VT[64][72] @0 ; per-wave scratch @4608+wid*1280
//  (scratch: PT[64][20] -> Y[16][72]); X region fully dead again by proj2 -> next-window stage
#define XBUF(b)   ((b) * 16384)
#define QK_SH     16384
#define LDS_BYTES 49152

__device__ __forceinline__ short f2b(float f) {
    __hip_bfloat16 h = __float2bfloat16(f);
    return __builtin_bit_cast(short, h);
}

__global__ void cvt_weights(const float* __restrict__ W1, const float* __restrict__ W2,
                            short* __restrict__ w1b, short* __restrict__ w2b) {
    int i = blockIdx.x * 256 + threadIdx.x;
    if (i < 192 * 768) w1b[i] = f2b(W1[i]);
    if (i < 768 * 64)  w2b[i] = f2b(W2[i]);
}

template<bool WSB>
__device__ __forceinline__ bf16x8 loadW(const short* __restrict__ wb,
                                        const float* __restrict__ wf, int off) {
    if (WSB) {
        return *(const bf16x8*)(wb + off);
    } else {
        f32x4 a = *(const f32x4*)(wf + off);
        f32x4 b = *(const f32x4*)(wf + off + 4);
        bf16x8 r;
        r[0] = f2b(a[0]); r[1] = f2b(a[1]); r[2] = f2b(a[2]); r[3] = f2b(a[3]);
        r[4] = f2b(b[0]); r[5] = f2b(b[1]); r[6] = f2b(b[2]); r[7] = f2b(b[3]);
        return r;
    }
}

__device__ __forceinline__ void gload_lds16(const float* g, unsigned char* l) {
    __builtin_amdgcn_global_load_lds(
        (const __attribute__((address_space(1))) void*)g,
        (__attribute__((address_space(3))) void*)l, 16, 0, 0);
}

#define VMWAIT(n) asm volatile("s_waitcnt vmcnt(" #n ")" ::: "memory")

// Stage 64-col f32 chunk kc of window XG -> X buffer b (4 gload_lds/wave).
#define STAGE_CHUNK(XG, kc, b) do {                                                 \
    _Pragma("unroll")                                                               \
    for (int j = 0; j < 4; ++j) {                                                   \
        int rr = (wid * 4 + j) * 4 + (lane >> 4);                                   \
        int ss = lane & 15;                                                         \
        const float* gsrc = (XG) + rr * 768 + (kc) * 64 + ((ss ^ (rr & 15)) << 2);  \
        gload_lds16(gsrc, &L[XBUF(b) + (wid * 4 + j) * 1024]);                      \
    }                                                                               \
} while (0)

#define WPREF(kc, W) do {                                                           \
    _Pragma("unroll")                                                               \
    for (int ks = 0; ks < 2; ++ks)                                                  \
        _Pragma("unroll")                                                           \
        for (int oi = 0; oi < 3; ++oi)                                              \
            W[ks*3+oi] = loadW<WSB>(W1b, W1f,                                       \
                (16*(wid+4*oi)+c)*768 + (kc)*64 + ks*32 + 8*g);                     \
} while (0)

#define COMPUTE(kc, b, W) do {                                                      \
    const unsigned char* Lb = &L[XBUF(b)];                                          \
    _Pragma("unroll")                                                               \
    for (int ks = 0; ks < 2; ++ks) {                                                \
        bf16x8 a[4];                                                                \
        _Pragma("unroll")                                                           \
        for (int rt = 0; rt < 4; ++rt) {                                            \
            int r = 16*rt + c;                                                      \
            int s0 = (8*ks + 2*g) ^ (r & 15);                                       \
            int s1 = (8*ks + 2*g + 1) ^ (r & 15);                                   \
            f32x4 lo = *(const f32x4*)(Lb + r*256 + s0*16);                         \
            f32x4 hi = *(const f32x4*)(Lb + r*256 + s1*16);                         \
            a[rt][0]=f2b(lo[0]); a[rt][1]=f2b(lo[1]);                               \
            a[rt][2]=f2b(lo[2]); a[rt][3]=f2b(lo[3]);                               \
            a[rt][4]=f2b(hi[0]); a[rt][5]=f2b(hi[1]);                               \
            a[rt][6]=f2b(hi[2]); a[rt][7]=f2b(hi[3]);                               \
        }                                                                           \
        _Pragma("unroll")                                                           \
        for (int oi = 0; oi < 3; ++oi)                                              \
            _Pragma("unroll")                                                       \
            for (int rt = 0; rt < 4; ++rt)                                          \
                acc1[rt*3+oi] = __builtin_amdgcn_mfma_f32_16x16x32_bf16(            \
                    a[rt], W[ks*3+oi], acc1[rt*3+oi], 0, 0, 0);                     \
    }                                                                               \
} while (0)

#define PIPE_ITER(XG, kc, b, Wc, Wn) do {                                           \
    if ((kc) != 11) { if constexpr (WSB) VMWAIT(10); else VMWAIT(16); }             \
    else            { if constexpr (WSB) VMWAIT(6);  else VMWAIT(12); }             \
    __builtin_amdgcn_sched_barrier(0);                                              \
    __builtin_amdgcn_s_barrier();                                                   \
    __builtin_amdgcn_sched_barrier(0);                                              \
    COMPUTE(kc, b, Wc);                                                             \
    if ((kc) + 1 < 12) WPREF((kc)+1, Wn);                                           \
    asm volatile("s_waitcnt lgkmcnt(0)" ::: "memory");                              \
    __builtin_amdgcn_sched_barrier(0);                                              \
    __builtin_amdgcn_s_barrier();                                                   \
    __builtin_amdgcn_sched_barrier(0);                                              \
    if ((kc) + 2 < 12) STAGE_CHUNK(XG, (kc)+2, b);                                  \
} while (0)

// One window: proj1 (async-pipelined) + attn + proj2.
// first: stage chunks 0,1 here (else they were staged during prev window's proj2).
// xgn != nullptr: during proj2, stage next window's chunks 0,1.
template<bool WSB>
__device__ __forceinline__ void do_window(
    const float* __restrict__ xg, const float* __restrict__ xgn, bool first,
    const float* __restrict__ W1f, const float* __restrict__ b1v,
    const float* __restrict__ W2f, const float* __restrict__ b2v,
    const short* __restrict__ W1b, const short* __restrict__ W2b,
    float* __restrict__ orow, unsigned char* L, short* S,
    int wid, int lane, int g, int c) {
    const f32x4 zero4 = {0.f, 0.f, 0.f, 0.f};

    // ---------------- proj1 ----------------
    f32x4 acc1[12];
    #pragma unroll
    for (int i = 0; i < 12; ++i) acc1[i] = zero4;

    bf16x8 Wa[6], Wb[6];
    if (first) { STAGE_CHUNK(xg, 0, 0); STAGE_CHUNK(xg, 1, 1); }
    WPREF(0, Wa);

    #pragma unroll 1
    for (int kc = 0; kc < 12; kc += 2) {
        PIPE_ITER(xg, kc,     0, Wa, Wb);
        PIPE_ITER(xg, kc + 1, 1, Wb, Wa);
    }
    __syncthreads();   // X strips dead -> VT/PT alias them

    // ---------------- bias + QKV -> LDS ----------------
    #pragma unroll
    for (int oi = 0; oi < 3; ++oi) {
        int ot = wid + 4 * oi;
        int o  = 16 * ot + c;
        float bias = b1v[o];
        #pragma unroll
        for (int rt = 0; rt < 4; ++rt) {
            f32x4 v = acc1[rt * 3 + oi];
            if (oi < 2) {        // Q (o<64), K (64..127): [n][o], stride 128
                #pragma unroll
                for (int r = 0; r < 4; ++r)
                    S[QK_SH + (16 * rt + 4 * g + r) * 128 + o] = f2b(v[r] + bias);
            } else {             // VT[d][n], stride 72, base 0
                int d = o - 128;
                s16x4 sv;
                sv[0] = f2b(v[0] + bias); sv[1] = f2b(v[1] + bias);
                sv[2] = f2b(v[2] + bias); sv[3] = f2b(v[3] + bias);
                *(s16x4*)&S[d * 72 + 16 * rt + 4 * g] = sv;
            }
        }
    }
    __syncthreads();

    // ---------------- S = Q K^T ----------------
    f32x4 sc[4];
    #pragma unroll
    for (int mt = 0; mt < 4; ++mt) sc[mt] = zero4;
    #pragma unroll
    for (int ks = 0; ks < 2; ++ks) {
        bf16x8 aq = *(const bf16x8*)&S[QK_SH + (16 * wid + c) * 128 + 32 * ks + 8 * g];
        #pragma unroll
        for (int mt = 0; mt < 4; ++mt) {
            bf16x8 bk = *(const bf16x8*)&S[QK_SH + (16 * mt + c) * 128 + 64 + 32 * ks + 8 * g];
            sc[mt] = __builtin_amdgcn_mfma_f32_16x16x32_bf16(aq, bk, sc[mt], 0, 0, 0);
        }
    }

    // ---------------- softmax ----------------
    float p[4][4];
    const float kS = 0.125f * 1.44269504088896f;
    #pragma unroll
    for (int r = 0; r < 4; ++r) {
        float m0 = fmaxf(fmaxf(sc[0][r], sc[1][r]), fmaxf(sc[2][r], sc[3][r]));
        m0 = fmaxf(m0, __shfl_xor(m0, 1));
        m0 = fmaxf(m0, __shfl_xor(m0, 2));
        m0 = fmaxf(m0, __shfl_xor(m0, 4));
        m0 = fmaxf(m0, __shfl_xor(m0, 8));
        float s0 = 0.f;
        float pr[4];
        #pragma unroll
        for (int mt = 0; mt < 4; ++mt) { pr[mt] = exp2f((sc[mt][r] - m0) * kS); s0 += pr[mt]; }
        s0 += __shfl_xor(s0, 1);
        s0 += __shfl_xor(s0, 2);
        s0 += __shfl_xor(s0, 4);
        s0 += __shfl_xor(s0, 8);
        float inv = __builtin_amdgcn_rcpf(s0);
        #pragma unroll
        for (int mt = 0; mt < 4; ++mt) p[mt][r] = pr[mt] * inv;
    }

    // ---------------- P^T -> per-wave scratch ----------------
    const int ptb = 4608 + wid * 1280;
    #pragma unroll
    for (int mt = 0; mt < 4; ++mt) {
        s16x4 sv;
        sv[0] = f2b(p[mt][0]); sv[1] = f2b(p[mt][1]);
        sv[2] = f2b(p[mt][2]); sv[3] = f2b(p[mt][3]);
        *(s16x4*)&S[ptb + (16 * mt + c) * 20 + 4 * g] = sv;
    }

    // ---------------- Y^T = V^T @ P^T ----------------
    f32x4 y4[4];
    #pragma unroll
    for (int it = 0; it < 4; ++it) y4[it] = zero4;
    #pragma unroll
    for (int ks = 0; ks < 2; ++ks) {
        bf16x8 pb;
        #pragma unroll
        for (int j = 0; j < 8; ++j)
            pb[j] = S[ptb + (32 * ks + 8 * g + j) * 20 + c];
        #pragma unroll
        for (int it = 0; it < 4; ++it) {
            bf16x8 av = *(const bf16x8*)&S[(16 * it + c) * 72 + 32 * ks + 8 * g];
            y4[it] = __builtin_amdgcn_mfma_f32_16x16x32_bf16(av, pb, y4[it], 0, 0, 0);
        }
    }
    // Y repack via scratch (aliases PT; this wave's PT reads done)
    #pragma unroll
    for (int it = 0; it < 4; ++it) {
        s16x4 sv;
        sv[0] = f2b(y4[it][0]); sv[1] = f2b(y4[it][1]);
        sv[2] = f2b(y4[it][2]); sv[3] = f2b(y4[it][3]);
        *(s16x4*)&S[ptb + c * 72 + 16 * it + 4 * g] = sv;
    }
    bf16x8 ay0 = *(const bf16x8*)&S[ptb + c * 72 + 8 * g];
    bf16x8 ay1 = *(const bf16x8*)&S[ptb + c * 72 + 32 + 8 * g];

    __syncthreads();   // all waves done reading VT/Y -> X region reusable for next window

    // ---------------- proj2 (+ stage next window's chunks 0,1) ----------------
    #pragma unroll 1
    for (int ch = 0; ch < 6; ++ch) {
        if (xgn) {
            if (ch == 0) STAGE_CHUNK(xgn, 0, 0);
            if (ch == 1) STAGE_CHUNK(xgn, 1, 1);
        }
        f32x4 a2[8];
        #pragma unroll
        for (int i = 0; i < 8; ++i) a2[i] = zero4;
        #pragma unroll
        for (int oi = 0; oi < 8; ++oi) {
            int off = (16 * (ch * 8 + oi) + c) * 64;
            bf16x8 bw0 = loadW<WSB>(W2b, W2f, off + 8 * g);
            a2[oi] = __builtin_amdgcn_mfma_f32_16x16x32_bf16(ay0, bw0, a2[oi], 0, 0, 0);
            bf16x8 bw1 = loadW<WSB>(W2b, W2f, off + 32 + 8 * g);
            a2[oi] = __builtin_amdgcn_mfma_f32_16x16x32_bf16(ay1, bw1, a2[oi], 0, 0, 0);
        }
        #pragma unroll
        for (int oi = 0; oi < 8; ++oi) {
            int o = 16 * (ch * 8 + oi) + c;
            float bias = b2v[o];
            #pragma unroll
            for (int r = 0; r < 4; ++r)
                orow[(size_t)(4 * g + r) * 768 + o] = a2[oi][r] + bias;
        }
    }
}

// One block per WINDOW PAIR. proj2(w0) prefetches w1's first X chunks so the read
// stream stays live through the write phase.
template<bool WSB>
__global__ __launch_bounds__(256, 3)
void tiny_att(const float* __restrict__ x, const float* __restrict__ W1f,
              const float* __restrict__ b1v, const float* __restrict__ W2f,
              const float* __restrict__ b2v, const short* __restrict__ W1b,
              const short* __restrict__ W2b, float* __restrict__ out, int nwin) {
    __shared__ __align__(16) unsigned char L[LDS_BYTES];
    short* S = (short*)L;
    const int tid  = threadIdx.x;
    const int wid  = tid >> 6;
    const int lane = tid & 63;
    const int g    = lane >> 4;
    const int c    = lane & 15;
    const int w0   = blockIdx.x * 2;
    const bool has2 = (w0 + 1) < nwin;
    const float* xg0 = x + (size_t)w0 * (64 * 768);
    const float* xg1 = xg0 + 64 * 768;
    float* o0 = out + ((size_t)w0 * 64 + 16 * wid) * 768;

    do_window<WSB>(xg0, has2 ? xg1 : nullptr, true,
                   W1f, b1v, W2f, b2v, W1b, W2b, o0, L, S, wid, lane, g, c);
    if (has2) {
        float* o1 = o0 + (size_t)64 * 768;
        do_window<WSB>(xg1, nullptr, false,
                       W1f, b1v, W2f, b2v, W1b, W2b, o1, L, S, wid, lane, g, c);
    }
}

extern "C" void kernel_launch(void* const* d_in, const int* in_sizes, int n_in,
                              void* d_out, int out_size, void* d_ws, size_t ws_size,
                              hipStream_t stream) {
    const float* x  = (const float*)d_in[0];
    const float* W1 = (const float*)d_in[1];
    const float* b1 = (const float*)d_in[2];
    const float* W2 = (const float*)d_in[3];
    const float* b2 = (const float*)d_in[4];
    float* out = (float*)d_out;
    const int nwin = in_sizes[0] / (64 * 768);   // 2048 windows
    const int npair = (nwin + 1) / 2;
    const size_t need = (size_t)(192 * 768 + 768 * 64) * sizeof(short);
    if (ws_size >= need) {
        short* w1b = (short*)d_ws;
        short* w2b = w1b + 192 * 768;
        cvt_weights<<<576, 256, 0, stream>>>(W1, W2, w1b, w2b);
        tiny_att<true><<<npair, 256, 0, stream>>>(x, W1, b1, W2, b2, w1b, w2b, out, nwin);
    } else {
        tiny_att<false><<<npair, 256, 0, stream>>>(x, W1, b1, W2, b2, nullptr, nullptr, out, nwin);
    }
}